// Round 13
// baseline (142.040 us; speedup 1.0000x reference)
//
#include <hip/hip_runtime.h>
#include <hip/hip_bf16.h>

typedef __bf16 bf16x8 __attribute__((ext_vector_type(8)));
typedef float  f32x4  __attribute__((ext_vector_type(4)));

// Async global->LDS DMA (no register result: compiler cannot re-roll/sink it).
__device__ __forceinline__ void dma16(const float* g, float* l) {
    typedef const __attribute__((address_space(1))) unsigned int* gp_t;
    typedef __attribute__((address_space(3))) unsigned int*       lp_t;
    __builtin_amdgcn_global_load_lds((gp_t)(const void*)g, (lp_t)(void*)l, 16, 0, 0);
}

// r11 step-shape + 2-way sharer fusion. Columns cp and cp+32 consume IDENTICAL
// A k-blocks (rowi[s][c] = c%16+16s; r12 validated numerically): one 8-wave
// block computes both -> each A fragment feeds 2 sharers (16 MFMA/step) -> A
// cache traffic 512->256 MB. Unlike r12 (mt-outer, B re-read 16x/step, LDS-
// bound): kb-OUTER/mt-inner so B fragments live in regs (bfr[2][2][4], 64
// VGPR, refreshed 16 ds_reads per 4 steps) and acc[4][2][4] (128 VGPR).
// Mechanism unchanged from r11: per-wave private LDS ring (depth 2 here; 64KB
// ring + 64KB B = 128KB -> 1 block/CU, 8 waves/CU), DMA with pre-swizzled
// source (linear dest, XOR rr<<4 on read), ZERO main-loop barriers, counted
// vmcnt never 0 mid-loop. Store bursts (32 dwords) must not cluster (6-bit
// vmcnt): chunk-0 acc stores spread into chunk-1 steps 0..3 (store-old ->
// zero -> accumulate); in-order counts exact: chunk-1 locals 1..4 wait
// vmcnt(36) = 32 stores + 4 loads younger than target, else vmcnt(4).
// Grid 256 = 1 block/CU exactly, one generation, no tail.
__global__ __launch_bounds__(512, 2) void sparse_linear_kernel(
    const float* __restrict__ A, const float* __restrict__ Bd,
    const int* __restrict__ rowi, const int* __restrict__ di,
    float* __restrict__ C)
{
    __shared__ __align__(16) float Aring[8][2][16 * 64];       // 64 KB
    __shared__ __align__(16) unsigned short Bt[8 * 64 * 64];   // 64 KB [j*4+kb][n][k]
    char* BtB = (char*)Bt;

    const int bid = blockIdx.x;
    const int cp  = bid & 31;          // pair (cp, cp+32); cp & cp+16 share A too -> same XCD (L2)
    const int grp = bid >> 5;          // 0..7 -> rows [grp*1024, +1024)
    const int t    = threadIdx.x;
    const int lane = t & 63;
    const int w    = t >> 6;           // 0..7

    int koff[4], dsj[2][4];
    #pragma unroll
    for (int s = 0; s < 4; ++s) {
        koff[s]   = rowi[s * 64 + cp] * 64;     // identical for cp+32 (r12-validated)
        dsj[0][s] = di[s * 64 + cp];
        dsj[1][s] = di[s * 64 + cp + 32];
    }

    const long wrow0 = (long)grp * 1024 + w * 64;   // + q*512 + mt*16

    // DMA one 16x64 fp32 step-tile into ring slot. Flat step st = q*16+kb*4+mt.
    auto dmaA = [&](int st, int slot) {
        if (st > 31) st = 31;                       // tail clamp (redundant, never read)
        const int q = st >> 4, kb = (st >> 2) & 3, mt = st & 3;
        float* slotp = &Aring[w][slot][0];
        const long rbase = wrow0 + q * 512 + mt * 16;
        #pragma unroll
        for (int i = 0; i < 4; ++i) {
            const int rr  = i * 4 + (lane >> 4);
            const int kfl = (((lane & 15) * 16) ^ (rr << 4)) >> 2;
            const float* g = A + (rbase + rr) * 4096 + koff[kb] + kfl;
            dma16(g, slotp + i * 256);
        }
    };

    // ---- prologue: fill slots 0,1 = steps 0,1 ----
    dmaA(0, 0);
    dmaA(1, 1);

    // ---- stage B once: thread t -> tile jj = j*4+kb, column n ----
    {
        const int jj = t >> 6;                      // 0..7
        const int n  = t & 63;
        const float* Bg = Bd + (long)dsj[jj >> 2][jj & 3] * 64 + n;   // row stride 16384
        char* dst = BtB + jj * 8192 + n * 128;
        const int sw = (n & 7) << 4;
        #pragma unroll
        for (int k4 = 0; k4 < 16; ++k4) {
            union { ushort4 u4; __bf16 e[4]; } pk;
            pk.e[0] = (__bf16)Bg[(long)(4 * k4 + 0) * 16384];
            pk.e[1] = (__bf16)Bg[(long)(4 * k4 + 1) * 16384];
            pk.e[2] = (__bf16)Bg[(long)(4 * k4 + 2) * 16384];
            pk.e[3] = (__bf16)Bg[(long)(4 * k4 + 3) * 16384];
            *(ushort4*)(dst + ((8 * k4) ^ sw)) = pk.u4;
        }
    }
    __syncthreads();   // the only barrier (drains prologue DMAs + B writes)

    f32x4 acc[4][2][4];   // [mt][j][n2] = 128 VGPR
    #pragma unroll
    for (int m = 0; m < 4; ++m)
        #pragma unroll
        for (int j = 0; j < 2; ++j)
            #pragma unroll
            for (int n2 = 0; n2 < 4; ++n2) acc[m][j][n2] = f32x4{0.f, 0.f, 0.f, 0.f};

    bf16x8 bfr[2][2][4];  // [j][kh][n2] for current kb, register-held 4 steps

    #pragma unroll 1
    for (int q = 0; q < 2; ++q) {
        #pragma unroll
        for (int local = 0; local < 16; ++local) {
            const int st = q * 16 + local;
            const int kb = local >> 2, mt = local & 3;
            const int slot = st & 1;

            // Counted wait (in-order retirement; target = refill issued at st-2)
            if (local >= 1 && local <= 4) {
                if (q == 1) asm volatile("s_waitcnt vmcnt(36)" ::: "memory");
                else        asm volatile("s_waitcnt vmcnt(4)"  ::: "memory");
            } else {
                asm volatile("s_waitcnt vmcnt(4)" ::: "memory");
            }
            __builtin_amdgcn_sched_barrier(0);

            // Spread chunk-0 C stores into chunk-1 steps 0..3 (store-old, zero)
            if (q == 1 && local < 4) {
                const int mts = local;
                const long crow0 = wrow0 + 0 * 512 + mts * 16 + (lane >> 4) * 4;
                #pragma unroll
                for (int j = 0; j < 2; ++j) {
                    const long col0 = (long)(cp + 32 * j) * 64 + (lane & 15);
                    #pragma unroll
                    for (int n2 = 0; n2 < 4; ++n2) {
                        #pragma unroll
                        for (int v = 0; v < 4; ++v)
                            __builtin_nontemporal_store(acc[mts][j][n2][v],
                                &C[(crow0 + v) * 4096 + col0 + n2 * 16]);
                        acc[mts][j][n2] = f32x4{0.f, 0.f, 0.f, 0.f};
                    }
                }
            }

            // B fragments: refresh once per kb (held in regs across 4 steps)
            if ((local & 3) == 0) {
                #pragma unroll
                for (int j = 0; j < 2; ++j) {
                    const char* bb = BtB + (j * 4 + kb) * 8192;
                    #pragma unroll
                    for (int kh = 0; kh < 2; ++kh)
                        #pragma unroll
                        for (int n2 = 0; n2 < 4; ++n2) {
                            const int nr = n2 * 16 + (lane & 15);
                            const int kbyte = kh * 64 + (lane >> 4) * 16;
                            bfr[j][kh][n2] = *(const bf16x8*)(bb + nr * 128 +
                                             (kbyte ^ ((nr & 7) << 4)));
                        }
                }
            }

            // A fragment: swizzled read from ring slot; convert fp32->bf16
            const char* ab = (const char*)&Aring[w][slot][0];
            const int r   = lane & 15;
            const int q32 = (lane >> 4) * 32;
            f32x4 a0 = *(const f32x4*)(ab + r * 256 + ((q32)            ^ (r << 4)));
            f32x4 a1 = *(const f32x4*)(ab + r * 256 + ((q32 + 16)       ^ (r << 4)));
            f32x4 a2 = *(const f32x4*)(ab + r * 256 + ((128 + q32)      ^ (r << 4)));
            f32x4 a3 = *(const f32x4*)(ab + r * 256 + ((128 + q32 + 16) ^ (r << 4)));
            union { bf16x8 v; __bf16 e[8]; } af0, af1;
            #pragma unroll
            for (int i = 0; i < 4; ++i) {
                af0.e[i]     = (__bf16)a0[i];
                af0.e[i + 4] = (__bf16)a1[i];
                af1.e[i]     = (__bf16)a2[i];
                af1.e[i + 4] = (__bf16)a3[i];
            }

            // 16 MFMAs: one A fragment x 2 sharers x 2 kh x 4 n2
            __builtin_amdgcn_s_setprio(1);
            #pragma unroll
            for (int kh = 0; kh < 2; ++kh) {
                const bf16x8 afv = kh ? af1.v : af0.v;
                #pragma unroll
                for (int j = 0; j < 2; ++j)
                    #pragma unroll
                    for (int n2 = 0; n2 < 4; ++n2)
                        acc[mt][j][n2] = __builtin_amdgcn_mfma_f32_16x16x32_bf16(
                            afv, bfr[j][kh][n2], acc[mt][j][n2], 0, 0, 0);
            }
            __builtin_amdgcn_s_setprio(0);

            // Refill this slot for step st+2 (every step; tail clamped)
            dmaA(st + 2, slot);
        }
    }

    // ---- tail: drain, then store chunk 1 ----
    asm volatile("s_waitcnt vmcnt(0)" ::: "memory");
    #pragma unroll
    for (int mts = 0; mts < 4; ++mts) {
        const long crow0 = wrow0 + 1 * 512 + mts * 16 + (lane >> 4) * 4;
        #pragma unroll
        for (int j = 0; j < 2; ++j) {
            const long col0 = (long)(cp + 32 * j) * 64 + (lane & 15);
            #pragma unroll
            for (int n2 = 0; n2 < 4; ++n2)
                #pragma unroll
                for (int v = 0; v < 4; ++v)
                    __builtin_nontemporal_store(acc[mts][j][n2][v],
                        &C[(crow0 + v) * 4096 + col0 + n2 * 16]);
        }
    }
}

extern "C" void kernel_launch(void* const* d_in, const int* in_sizes, int n_in,
                              void* d_out, int out_size, void* d_ws, size_t ws_size,
                              hipStream_t stream) {
    const float* A    = (const float*)d_in[0];
    const float* Bd   = (const float*)d_in[1];
    const int*   rowi = (const int*)d_in[2];
    const int*   di   = (const int*)d_in[3];
    float*       C    = (float*)d_out;

    dim3 grid(8 * 32);    // 8 row-groups x 32 sharer-pairs = 256 blocks = 1/CU
    dim3 block(512);
    hipLaunchKernelGGL(sparse_linear_kernel, grid, block, 0, stream,
                       A, Bd, rowi, di, C);
}

// Round 14
// 72.079 us; speedup vs baseline: 1.9706x; 1.9706x over previous
//
#include <hip/hip_runtime.h>
#include <hip/hip_bf16.h>

typedef __bf16 bf16x8 __attribute__((ext_vector_type(8)));
typedef float  f32x4  __attribute__((ext_vector_type(4)));

// Async global->LDS DMA (no register result: compiler cannot re-roll/sink it).
__device__ __forceinline__ void dma16(const float* g, float* l) {
    typedef const __attribute__((address_space(1))) unsigned int* gp_t;
    typedef __attribute__((address_space(3))) unsigned int*       lp_t;
    __builtin_amdgcn_global_load_lds((gp_t)(const void*)g, (lp_t)(void*)l, 16, 0, 0);
}

// 2-way sharer fusion (cp, cp+32 share identical A k-blocks; r12/r13-verified)
// on the r11 DMA-ring mechanism, sized to NOT spill (r13 lesson: acc[4][2][4]
// = 128 + bfr 64 -> allocator granted 128 and spilled, 142us). Conservation:
// acc = 32*mtN, bfr = 64 amortized over mtN steps. mtN=2 here: acc[2][2][4]
// = 64 + bfr[2][2][4] = 64 -> ~r11 pressure; 8 ds_read_b128/step (same
// aggregate LDS load as r11 since each step does 2x MFMA work in half steps).
// Mechanism (r9/r11-proven): per-wave private depth-2 LDS ring, DMA with
// pre-swizzled source (linear dest, XOR rr<<4 on read, 0 conflicts), zero
// main-loop barriers, counted vmcnt never 0 mid-loop. Chunk = 2 mt x 4 kb =
// 8 steps; chunk-q stores (32 dwords/step) spread into chunk-(q+1) locals
// 0-1, store-old->zero->accumulate; in-order exact: locals 1-2 of q>=1 wait
// vmcnt(36) = 32 stores + 4 loads younger than target, else vmcnt(4).
// LDS 64KB ring + 64KB B = 128KB -> 1 block/CU (8 waves); grid 256 = 1/CU.
__global__ __launch_bounds__(512, 2) void sparse_linear_kernel(
    const float* __restrict__ A, const float* __restrict__ Bd,
    const int* __restrict__ rowi, const int* __restrict__ di,
    float* __restrict__ C)
{
    __shared__ __align__(16) float Aring[8][2][16 * 64];       // 64 KB
    __shared__ __align__(16) unsigned short Bt[8 * 64 * 64];   // 64 KB [j*4+kb][n][k]
    char* BtB = (char*)Bt;

    const int bid = blockIdx.x;
    const int cp  = bid & 31;          // sharer pair (cp, cp+32)
    const int grp = bid >> 5;          // 0..7 -> rows [grp*1024, +1024)
    const int t    = threadIdx.x;
    const int lane = t & 63;
    const int w    = t >> 6;           // 0..7

    int koff[4], dsj[2][4];
    #pragma unroll
    for (int s = 0; s < 4; ++s) {
        koff[s]   = rowi[s * 64 + cp] * 64;     // identical for cp+32
        dsj[0][s] = di[s * 64 + cp];
        dsj[1][s] = di[s * 64 + cp + 32];
    }

    const long wrow0 = (long)grp * 1024 + w * 128;   // + q*32 + mt*16

    // DMA one 16x64 fp32 step-tile into ring slot. st = q*8 + kb*2 + mt.
    auto dmaA = [&](int st, int slot) {
        if (st > 31) st = 31;                        // tail clamp (redundant, never read)
        const int q = st >> 3, kb = (st >> 1) & 3, mt = st & 1;
        float* slotp = &Aring[w][slot][0];
        const long rbase = wrow0 + q * 32 + mt * 16;
        #pragma unroll
        for (int i = 0; i < 4; ++i) {
            const int rr  = i * 4 + (lane >> 4);
            const int kfl = (((lane & 15) * 16) ^ (rr << 4)) >> 2;
            const float* g = A + (rbase + rr) * 4096 + koff[kb] + kfl;
            dma16(g, slotp + i * 256);
        }
    };

    // ---- prologue: fill slots 0,1 = steps 0,1 ----
    dmaA(0, 0);
    dmaA(1, 1);

    // ---- stage B once: thread t -> tile jj = j*4+kb, column n ----
    {
        const int jj = t >> 6;                       // 0..7
        const int n  = t & 63;
        const float* Bg = Bd + (long)dsj[jj >> 2][jj & 3] * 64 + n;   // row stride 16384
        char* dst = BtB + jj * 8192 + n * 128;
        const int sw = (n & 7) << 4;
        #pragma unroll
        for (int k4 = 0; k4 < 16; ++k4) {
            union { ushort4 u4; __bf16 e[4]; } pk;
            pk.e[0] = (__bf16)Bg[(long)(4 * k4 + 0) * 16384];
            pk.e[1] = (__bf16)Bg[(long)(4 * k4 + 1) * 16384];
            pk.e[2] = (__bf16)Bg[(long)(4 * k4 + 2) * 16384];
            pk.e[3] = (__bf16)Bg[(long)(4 * k4 + 3) * 16384];
            *(ushort4*)(dst + ((8 * k4) ^ sw)) = pk.u4;
        }
    }
    __syncthreads();   // the only barrier (drains prologue DMAs + B writes)

    f32x4 acc[2][2][4];   // [mt][j][n2] = 64 VGPR
    #pragma unroll
    for (int m = 0; m < 2; ++m)
        #pragma unroll
        for (int j = 0; j < 2; ++j)
            #pragma unroll
            for (int n2 = 0; n2 < 4; ++n2) acc[m][j][n2] = f32x4{0.f, 0.f, 0.f, 0.f};

    bf16x8 bfr[2][2][4];  // [j][kh][n2] for current kb = 64 VGPR, held 2 steps

    #pragma unroll 1
    for (int q = 0; q < 4; ++q) {
        #pragma unroll
        for (int local = 0; local < 8; ++local) {
            const int st = q * 8 + local;
            const int kb = local >> 1, mt = local & 1;
            const int slot = st & 1;

            // Counted wait (in-order; target = refill issued at st-2)
            if (q >= 1 && (local == 1 || local == 2))
                asm volatile("s_waitcnt vmcnt(36)" ::: "memory");
            else
                asm volatile("s_waitcnt vmcnt(4)" ::: "memory");
            __builtin_amdgcn_sched_barrier(0);

            // Spread prev chunk's C stores into locals 0-1 (store-old, zero)
            if (q >= 1 && local < 2) {
                const int mts = local;
                const long crow0 = wrow0 + (q - 1) * 32 + mts * 16 + (lane >> 4) * 4;
                #pragma unroll
                for (int j = 0; j < 2; ++j) {
                    const long col0 = (long)(cp + 32 * j) * 64 + (lane & 15);
                    #pragma unroll
                    for (int n2 = 0; n2 < 4; ++n2) {
                        #pragma unroll
                        for (int v = 0; v < 4; ++v)
                            __builtin_nontemporal_store(acc[mts][j][n2][v],
                                &C[(crow0 + v) * 4096 + col0 + n2 * 16]);
                        acc[mts][j][n2] = f32x4{0.f, 0.f, 0.f, 0.f};
                    }
                }
            }

            // B fragments: refresh once per kb (held in regs across 2 steps)
            if (mt == 0) {
                #pragma unroll
                for (int j = 0; j < 2; ++j) {
                    const char* bb = BtB + (j * 4 + kb) * 8192;
                    #pragma unroll
                    for (int kh = 0; kh < 2; ++kh)
                        #pragma unroll
                        for (int n2 = 0; n2 < 4; ++n2) {
                            const int nr = n2 * 16 + (lane & 15);
                            const int kbyte = kh * 64 + (lane >> 4) * 16;
                            bfr[j][kh][n2] = *(const bf16x8*)(bb + nr * 128 +
                                             (kbyte ^ ((nr & 7) << 4)));
                        }
                }
            }

            // A fragment: swizzled read from ring slot; convert fp32->bf16
            const char* ab = (const char*)&Aring[w][slot][0];
            const int r   = lane & 15;
            const int q32 = (lane >> 4) * 32;
            f32x4 a0 = *(const f32x4*)(ab + r * 256 + ((q32)            ^ (r << 4)));
            f32x4 a1 = *(const f32x4*)(ab + r * 256 + ((q32 + 16)       ^ (r << 4)));
            f32x4 a2 = *(const f32x4*)(ab + r * 256 + ((128 + q32)      ^ (r << 4)));
            f32x4 a3 = *(const f32x4*)(ab + r * 256 + ((128 + q32 + 16) ^ (r << 4)));
            union { bf16x8 v; __bf16 e[8]; } af0, af1;
            #pragma unroll
            for (int i = 0; i < 4; ++i) {
                af0.e[i]     = (__bf16)a0[i];
                af0.e[i + 4] = (__bf16)a1[i];
                af1.e[i]     = (__bf16)a2[i];
                af1.e[i + 4] = (__bf16)a3[i];
            }

            // 16 MFMAs: one A fragment x 2 sharers x 2 kh x 4 n2
            __builtin_amdgcn_s_setprio(1);
            #pragma unroll
            for (int kh = 0; kh < 2; ++kh) {
                const bf16x8 afv = kh ? af1.v : af0.v;
                #pragma unroll
                for (int j = 0; j < 2; ++j)
                    #pragma unroll
                    for (int n2 = 0; n2 < 4; ++n2)
                        acc[mt][j][n2] = __builtin_amdgcn_mfma_f32_16x16x32_bf16(
                            afv, bfr[j][kh][n2], acc[mt][j][n2], 0, 0, 0);
            }
            __builtin_amdgcn_s_setprio(0);

            // Refill this slot for step st+2 (every step; tail clamped)
            dmaA(st + 2, slot);
        }
    }

    // ---- tail: drain, then store the last chunk (q=3) ----
    asm volatile("s_waitcnt vmcnt(0)" ::: "memory");
    #pragma unroll
    for (int mts = 0; mts < 2; ++mts) {
        const long crow0 = wrow0 + 3 * 32 + mts * 16 + (lane >> 4) * 4;
        #pragma unroll
        for (int j = 0; j < 2; ++j) {
            const long col0 = (long)(cp + 32 * j) * 64 + (lane & 15);
            #pragma unroll
            for (int n2 = 0; n2 < 4; ++n2)
                #pragma unroll
                for (int v = 0; v < 4; ++v)
                    __builtin_nontemporal_store(acc[mts][j][n2][v],
                        &C[(crow0 + v) * 4096 + col0 + n2 * 16]);
        }
    }
}

extern "C" void kernel_launch(void* const* d_in, const int* in_sizes, int n_in,
                              void* d_out, int out_size, void* d_ws, size_t ws_size,
                              hipStream_t stream) {
    const float* A    = (const float*)d_in[0];
    const float* Bd   = (const float*)d_in[1];
    const int*   rowi = (const int*)d_in[2];
    const int*   di   = (const int*)d_in[3];
    float*       C    = (float*)d_out;

    dim3 grid(8 * 32);    // 8 row-groups x 32 sharer-pairs = 256 blocks = 1/CU
    dim3 block(512);
    hipLaunchKernelGGL(sparse_linear_kernel, grid, block, 0, stream,
                       A, Bd, rowi, di, C);
}

// Round 15
// 66.796 us; speedup vs baseline: 2.1265x; 1.0791x over previous
//
#include <hip/hip_runtime.h>
#include <hip/hip_bf16.h>

typedef __bf16 bf16x8 __attribute__((ext_vector_type(8)));
typedef float  f32x4  __attribute__((ext_vector_type(4)));

// Async global->LDS DMA (no register result: compiler cannot re-roll/sink it).
__device__ __forceinline__ void dma16(const float* g, float* l) {
    typedef const __attribute__((address_space(1))) unsigned int* gp_t;
    typedef __attribute__((address_space(3))) unsigned int*       lp_t;
    __builtin_amdgcn_global_load_lds((gp_t)(const void*)g, (lp_t)(void*)l, 16, 0, 0);
}

// EXACT r11 (best: 56.3us) with ONE change: C stores are plain cached stores,
// not nontemporal. Theory: NT scalar-dword stores bypass L2/L3, so each store
// instruction's 4x 64B row-segments hit HBM as partial lines -> write path
// (147MB, 2/3 of traffic) capped ~2.6TB/s = the observed floor. Cached stores
// let L2 write-combine the 4 adjacent 64B segments per 256B line, and dirty C
// lines rewritten every graph replay can stay L3-resident (A 128MB + C 128MB
// ~ L3 256MB; FETCH=70MB already shows L3 holding half of A across replays).
// Everything else identical to r11: persistent 512 blocks (64c x 8 rowgrp) =
// 2/CU, per-wave private 3-slot DMA ring, pre-swizzled source (linear dest,
// XOR rr<<4 on read, 0 conflicts), zero main-loop barriers, counted vmcnt
// (never 0 mid-loop), B staged once, bfr register-held per kb.
__global__ __launch_bounds__(256, 2) void sparse_linear_kernel(
    const float* __restrict__ A, const float* __restrict__ Bd,
    const int* __restrict__ rowi, const int* __restrict__ di,
    float* __restrict__ C)
{
    __shared__ __align__(16) float Aring[4][3][16 * 64];       // 48 KB
    __shared__ __align__(16) unsigned short Bt[4 * 64 * 64];   // 32 KB
    char* BtB = (char*)Bt;

    const int bid = blockIdx.x;
    const int c   = bid & 63;
    const int grp = bid >> 6;          // 0..7 -> rows [grp*1024, +1024)
    const int t    = threadIdx.x;
    const int lane = t & 63;
    const int w    = t >> 6;           // 0..3

    int rs[4], ds[4];
    #pragma unroll
    for (int s = 0; s < 4; ++s) {
        rs[s] = rowi[s * 64 + c];
        ds[s] = di[s * 64 + c];
    }
    int koff[4];
    #pragma unroll
    for (int s = 0; s < 4; ++s) koff[s] = rs[s] * 64;

    const long wrow0 = (long)grp * 1024 + w * 64;   // + q*256 + mt*16

    auto dmaA = [&](int q, int kb, int mt, int slot) {
        float* slotp = &Aring[w][slot][0];
        #pragma unroll
        for (int i = 0; i < 4; ++i) {
            const int rr  = i * 4 + (lane >> 4);
            const int kfl = (((lane & 15) * 16) ^ (rr << 4)) >> 2;
            const float* g = A + (wrow0 + q * 256 + mt * 16 + rr) * 4096 + koff[kb] + kfl;
            dma16(g, slotp + i * 256);
        }
    };

    // ---- prologue: fill slots 0..2 = steps 0..2 (q=0, kb=0, mt=0,1,2) ----
    dmaA(0, 0, 0, 0);
    dmaA(0, 0, 1, 1);
    dmaA(0, 0, 2, 2);

    // ---- stage B once: wave sb stages block sb; lane n owns column n ----
    {
        const int n  = t & 63;
        const int sb = t >> 6;
        const float* Bg = Bd + (long)ds[sb] * 64 + n;   // row stride = BN*TB = 16384
        char* dst = BtB + sb * 8192 + n * 128;
        const int sw = (n & 7) << 4;
        #pragma unroll
        for (int k4 = 0; k4 < 16; ++k4) {
            union { ushort4 u4; __bf16 e[4]; } pk;
            pk.e[0] = (__bf16)Bg[(long)(4 * k4 + 0) * 16384];
            pk.e[1] = (__bf16)Bg[(long)(4 * k4 + 1) * 16384];
            pk.e[2] = (__bf16)Bg[(long)(4 * k4 + 2) * 16384];
            pk.e[3] = (__bf16)Bg[(long)(4 * k4 + 3) * 16384];
            *(ushort4*)(dst + ((8 * k4) ^ sw)) = pk.u4;
        }
    }
    __syncthreads();   // the only barrier (drains prologue DMAs + B writes)

    f32x4 acc[4][4];   // [mt][n2] for the current chunk
    #pragma unroll
    for (int m = 0; m < 4; ++m)
        #pragma unroll
        for (int n2 = 0; n2 < 4; ++n2) acc[m][n2] = f32x4{0.f, 0.f, 0.f, 0.f};

    bf16x8 bfr[2][4];  // B fragments of current kb, register-held 4 steps

    #pragma unroll 1
    for (int q = 0; q < 4; ++q) {
        const int qm3 = q % 3;   // slot base: (16q+local)%3 = (q+local)%3

        #pragma unroll
        for (int local = 0; local < 16; ++local) {
            const int kb = local >> 2, mt = local & 3;
            int slot = qm3 + (local % 3);
            if (slot >= 3) slot -= 3;

            // Counted wait (in-order retirement): boundary-adjacent steps see
            // 16 younger stores + 8 younger load-groups -> 24; else 8.
            if (local < 3) asm volatile("s_waitcnt vmcnt(24)" ::: "memory");
            else           asm volatile("s_waitcnt vmcnt(8)"  ::: "memory");
            __builtin_amdgcn_sched_barrier(0);

            // B fragments: refresh once per kb (register-held across 4 steps)
            if (mt == 0) {
                const char* bbase = BtB + kb * 8192;
                #pragma unroll
                for (int kh = 0; kh < 2; ++kh)
                    #pragma unroll
                    for (int n2 = 0; n2 < 4; ++n2) {
                        const int nr = n2 * 16 + (lane & 15);
                        const int kbyte = kh * 64 + (lane >> 4) * 16;
                        bfr[kh][n2] = *(const bf16x8*)(bbase + nr * 128 + (kbyte ^ ((nr & 7) << 4)));
                    }
            }

            // A fragment: swizzled read from ring slot; convert fp32->bf16
            const char* ab = (const char*)&Aring[w][slot][0];
            const int r   = lane & 15;
            const int q32 = (lane >> 4) * 32;
            f32x4 a0 = *(const f32x4*)(ab + r * 256 + ((q32)            ^ (r << 4)));
            f32x4 a1 = *(const f32x4*)(ab + r * 256 + ((q32 + 16)       ^ (r << 4)));
            f32x4 a2 = *(const f32x4*)(ab + r * 256 + ((128 + q32)      ^ (r << 4)));
            f32x4 a3 = *(const f32x4*)(ab + r * 256 + ((128 + q32 + 16) ^ (r << 4)));
            union { bf16x8 v; __bf16 e[8]; } af0, af1;
            #pragma unroll
            for (int i = 0; i < 4; ++i) {
                af0.e[i]     = (__bf16)a0[i];
                af0.e[i + 4] = (__bf16)a1[i];
                af1.e[i]     = (__bf16)a2[i];
                af1.e[i + 4] = (__bf16)a3[i];
            }

            // 8 MFMAs for this (kb, mt)
            __builtin_amdgcn_s_setprio(1);
            #pragma unroll
            for (int kh = 0; kh < 2; ++kh) {
                const bf16x8 afv = kh ? af1.v : af0.v;
                #pragma unroll
                for (int n2 = 0; n2 < 4; ++n2)
                    acc[mt][n2] = __builtin_amdgcn_mfma_f32_16x16x32_bf16(afv, bfr[kh][n2], acc[mt][n2], 0, 0, 0);
            }
            __builtin_amdgcn_s_setprio(0);

            // Refill this slot for step+3 (every step; tail clamped).
            {
                int l2 = local + 3, q2 = q;
                if (l2 >= 16) { l2 -= 16; ++q2; }
                if (q2 > 3) q2 = 3;                 // harmless redundant DMA at tail
                dmaA(q2, l2 >> 2, l2 & 3, slot);
            }

            // Chunk boundary: store this chunk's C — PLAIN cached stores (the
            // single change vs r11): L2 write-combines the 64B segments into
            // full lines; dirty C lines can stay L3-resident across replays.
            if (local == 15) {
                __builtin_amdgcn_sched_barrier(0);
                #pragma unroll
                for (int mts = 0; mts < 4; ++mts) {
                    const long crow0 = wrow0 + q * 256 + mts * 16 + (lane >> 4) * 4;
                    const long col0  = (long)c * 64 + (lane & 15);
                    #pragma unroll
                    for (int n2 = 0; n2 < 4; ++n2) {
                        #pragma unroll
                        for (int v = 0; v < 4; ++v)
                            C[(crow0 + v) * 4096 + col0 + n2 * 16] = acc[mts][n2][v];
                        acc[mts][n2] = f32x4{0.f, 0.f, 0.f, 0.f};
                    }
                }
                __builtin_amdgcn_sched_barrier(0);
            }
        }
    }

    asm volatile("s_waitcnt vmcnt(0)" ::: "memory");   // drain tail DMAs/stores
}

extern "C" void kernel_launch(void* const* d_in, const int* in_sizes, int n_in,
                              void* d_out, int out_size, void* d_ws, size_t ws_size,
                              hipStream_t stream) {
    const float* A    = (const float*)d_in[0];
    const float* Bd   = (const float*)d_in[1];
    const int*   rowi = (const int*)d_in[2];
    const int*   di   = (const int*)d_in[3];
    float*       C    = (float*)d_out;

    dim3 grid(8 * 64);    // 8 row-groups x 64 columns = 512 blocks = 2/CU, 1 generation
    dim3 block(256);
    hipLaunchKernelGGL(sparse_linear_kernel, grid, block, 0, stream,
                       A, Bd, rowi, di, C);
}